// Round 8
// baseline (380.178 us; speedup 1.0000x reference)
//
#include <hip/hip_runtime.h>
#include <hip/hip_bf16.h>
#include <cstdint>

typedef __bf16 bf16;
typedef __bf16 bf16x8 __attribute__((ext_vector_type(8)));
typedef __bf16 bf16x4 __attribute__((ext_vector_type(4)));
typedef __bf16 bf16x2 __attribute__((ext_vector_type(2)));
typedef float floatx4 __attribute__((ext_vector_type(4)));
typedef float f32x16 __attribute__((ext_vector_type(16)));
typedef int intx4 __attribute__((ext_vector_type(4)));

#define MFMA16(a, b, c) __builtin_amdgcn_mfma_f32_16x16x32_bf16(a, b, c, 0, 0, 0)
#define MFMA32(a, b, c) __builtin_amdgcn_mfma_f32_32x32x16_bf16(a, b, c, 0, 0, 0)

__device__ __forceinline__ void gload_lds16(const void* g, void* l) {
    __builtin_amdgcn_global_load_lds(
        (const __attribute__((address_space(1))) void*)g,
        (__attribute__((address_space(3))) void*)l, 16, 0, 0);
}

__device__ __forceinline__ int pack2(float a, float b) {
    union { bf16x2 v; int u; } z;
    z.v[0] = (bf16)a;
    z.v[1] = (bf16)b;
    return z.u;
}

// ---------------------------------------------------------------------------
// Fused prep (kept: measured ~-12 us vs 3 separate launches).
//   blocks [0, 8192):      downcast x -> xb
//   blocks [8192, 20480):  transpose Wqkv [2048][6144] -> WqkvT
//   blocks [20480, 24576): transpose Wo   [2048][2048] -> WoT
// ---------------------------------------------------------------------------
__global__ __launch_bounds__(256) void prep_kernel(
    const float* __restrict__ x, const float* __restrict__ Wqkv,
    const float* __restrict__ Wo, bf16* __restrict__ xb,
    bf16* __restrict__ WqkvT, bf16* __restrict__ WoT) {
    __shared__ float tile[32][33];
    const int bid = blockIdx.x;
    const int tid = threadIdx.x;

    if (bid < 8192) {
        const size_t i = ((size_t)bid * 256 + tid) * 4;
        const float4 v = *(const float4*)(x + i);
        bf16x4 o = {(bf16)v.x, (bf16)v.y, (bf16)v.z, (bf16)v.w};
        *(bf16x4*)(xb + i) = o;
        return;
    }

    const float* in;
    bf16* out;
    int R, C, bx, by;
    if (bid < 20480) {
        const int b = bid - 8192;
        in = Wqkv; out = WqkvT; R = 2048; C = 6144;
        bx = b % 192; by = b / 192;
    } else {
        const int b = bid - 20480;
        in = Wo; out = WoT; R = 2048; C = 2048;
        bx = b & 63; by = b >> 6;
    }
    const int c0 = bx * 32, r0 = by * 32;
    const int tx = tid & 31, ty = tid >> 5;
    for (int i = 0; i < 32; i += 8)
        tile[ty + i][tx] = in[(size_t)(r0 + ty + i) * C + (c0 + tx)];
    __syncthreads();
    for (int i = 0; i < 32; i += 8)
        out[(size_t)(c0 + ty + i) * R + (r0 + tx)] = (bf16)tile[tx][ty + i];
}

// ---------------------------------------------------------------------------
// GEMM: C[M][N] = A[M][K] @ BT[N][K]^T   (bf16 in, fp32 accum)
// Verified 128x128 m97-structure (~117 us for qkv, 866 TF). The 256^2
// 8-phase was tried THREE times (R1/R5/R7: 140/149/144 us, MfmaUtil 28-29,
// invariant to wait discipline & stage placement) -> retired permanently.
// This structure is the session's qkv ceiling.
// MODE 0: epilogue scatters to q/k/v (N = 6144 = [3][16][128])
// MODE 1: epilogue writes FP32 C row-major [M][N]
// ---------------------------------------------------------------------------
template <int MODE>
__global__ __launch_bounds__(256) void gemm_bt_kernel(
    const bf16* __restrict__ A, const bf16* __restrict__ BT,
    int M, int N, int K,
    bf16* __restrict__ qt, bf16* __restrict__ kt, bf16* __restrict__ vt,
    float* __restrict__ Cout) {
    __shared__ alignas(16) bf16 As[128 * 64];  // 16 KB
    __shared__ alignas(16) bf16 Bs[128 * 64];  // 16 KB

    const int tid = threadIdx.x;
    const int wave = tid >> 6, lane = tid & 63;
    const int quad = lane >> 4, r16 = lane & 15;
    const int m0 = blockIdx.y * 128, n0 = blockIdx.x * 128;
    const int wm = (wave >> 1) * 64, wn = (wave & 1) * 64;

    // staging map: 4 chunks per matrix per thread; chunk c: row=c>>3, sp=c&7,
    // global seg s = sp ^ (row&7)
    int srow[4], soff[4];
#pragma unroll
    for (int j = 0; j < 4; ++j) {
        const int c = tid + j * 256;
        srow[j] = c >> 3;
        soff[j] = ((c & 7) ^ (srow[j] & 7)) * 8;
    }

    floatx4 acc[4][4] = {};

    for (int k0 = 0; k0 < K; k0 += 64) {
        __syncthreads();
#pragma unroll
        for (int j = 0; j < 4; ++j) {
            const int c = tid + j * 256;
            gload_lds16(A + (size_t)(m0 + srow[j]) * K + k0 + soff[j], As + c * 8);
            gload_lds16(BT + (size_t)(n0 + srow[j]) * K + k0 + soff[j], Bs + c * 8);
        }
        __syncthreads();

#pragma unroll
        for (int kc = 0; kc < 2; ++kc) {
            bf16x8 a[4], b[4];
#pragma unroll
            for (int i = 0; i < 4; ++i) {
                const int row = wm + i * 16 + r16;
                const int sp = (4 * kc + quad) ^ (row & 7);
                a[i] = *(const bf16x8*)(As + row * 64 + sp * 8);
            }
#pragma unroll
            for (int j = 0; j < 4; ++j) {
                const int row = wn + j * 16 + r16;
                const int sp = (4 * kc + quad) ^ (row & 7);
                b[j] = *(const bf16x8*)(Bs + row * 64 + sp * 8);
            }
#pragma unroll
            for (int i = 0; i < 4; ++i)
#pragma unroll
                for (int j = 0; j < 4; ++j)
                    acc[i][j] = MFMA16(a[i], b[j], acc[i][j]);
        }
    }

    if (MODE == 0) {
        const int t = n0 >> 11;  // block-uniform: which of q/k/v
        const float qscale = 0.08838834764831845f;  // 128^-0.5
#pragma unroll
        for (int i = 0; i < 4; ++i) {
            const int mbase = m0 + wm + i * 16 + quad * 4;
            const int b_ = mbase >> 11;
            const int s = mbase & 2047;
#pragma unroll
            for (int j = 0; j < 4; ++j) {
                const int n = n0 + wn + j * 16 + r16;
                const int h = (n >> 7) & 15, hd = n & 127;
                const int bh = b_ * 16 + h;
                if (t == 0) {
#pragma unroll
                    for (int r = 0; r < 4; ++r)
                        qt[(size_t)(bh * 2048 + s + r) * 128 + hd] =
                            (bf16)(acc[i][j][r] * qscale);
                } else if (t == 1) {
#pragma unroll
                    for (int r = 0; r < 4; ++r)
                        kt[(size_t)(bh * 2048 + s + r) * 128 + hd] = (bf16)acc[i][j][r];
                } else {
                    bf16x4 pv = {(bf16)acc[i][j][0], (bf16)acc[i][j][1],
                                 (bf16)acc[i][j][2], (bf16)acc[i][j][3]};
                    *(bf16x4*)(vt + (size_t)(bh * 128 + hd) * 2048 + s) = pv;
                }
            }
        }
    } else {
#pragma unroll
        for (int i = 0; i < 4; ++i) {
            const int mbase = m0 + wm + i * 16 + quad * 4;
#pragma unroll
            for (int j = 0; j < 4; ++j) {
                const int n = n0 + wn + j * 16 + r16;
#pragma unroll
                for (int r = 0; r < 4; ++r)
                    Cout[(size_t)(mbase + r) * N + n] = acc[i][j][r];
            }
        }
    }
}

// ---------------------------------------------------------------------------
// Flash attention (causal), no-max softmax. Core unchanged from R4
// (verified): swapped QK^T (32x32x16), in-register P via pack+shfl_xor(32),
// K/V dbuf stage-early pipeline, 64 KB LDS, 2 blocks/CU.
//
// NEW (R8, T1): XCD-grouped block mapping. The 16 q-tile blocks of one bh
// read the SAME 2 MB K/V; default dispatch scatters them across all 8 XCDs
// (every block streams from L3). Remap so xcd = flat&7 is constant per
// bh-group: all 16 sharers land on one XCD -> K/V L2-resident (64 MB total
// K/V vs 32 MB aggregate L2 makes locality real). Balance preserved: CU c
// gets tslots s and 15-s (blocks w, w+256) -> uniform 34 iters, same
// round-robin assumption as the old by->t pairing. Pure bijection: worst
// case is a permutation (neutral).
// ---------------------------------------------------------------------------
__global__ __launch_bounds__(256, 2) void attn_kernel(
    const bf16* __restrict__ qt, const bf16* __restrict__ kt,
    const bf16* __restrict__ vt, bf16* __restrict__ o) {
    __shared__ alignas(16) bf16 Ks[2][64 * 128];   // (row,sp): seg = sp ^ (row&15)
    __shared__ alignas(16) bf16 Vts[2][128 * 64];  // (row,sp): seg = sp ^ (row&7)

    const int tid = threadIdx.x;
    const int wave = tid >> 6, lane = tid & 63;
    const int l31 = lane & 31, h = lane >> 5;

    // XCD-grouped remap: flat -> (xcd, bh, tslot); same-bh blocks share XCD.
    const int flat = blockIdx.y * 32 + blockIdx.x;
    const int xcd = flat & 7, idx = flat >> 3;
    const int bh = xcd * 4 + (idx & 3);
    const int tslot = idx >> 2;
    const int t = tslot < 8 ? tslot : 23 - tslot;  // CU gets s & 15-s: 34 iters
    const int b_ = bh >> 4, hh = bh & 15;

    const int q0 = t * 128;
    const int qbase = q0 + wave * 32;
    const int qrow = qbase + l31;

    bf16x8 aq[8];
    {
        const bf16* qr = qt + (((size_t)bh * 2048 + qrow) << 7);
#pragma unroll
        for (int s = 0; s < 8; ++s)
            aq[s] = *(const bf16x8*)(qr + s * 16 + h * 8);
    }

    auto stageKV = [&](int buf, int k0) {
#pragma unroll
        for (int j = 0; j < 4; ++j) {
            const int c = tid + j * 256;
            const int row = c >> 4, sp = c & 15, s = sp ^ (row & 15);
            gload_lds16(kt + (((size_t)bh * 2048 + k0 + row) << 7) + s * 8,
                        &Ks[buf][c * 8]);
        }
#pragma unroll
        for (int j = 0; j < 4; ++j) {
            const int c = tid + j * 256;
            const int row = c >> 3, sp = c & 7, s = sp ^ (row & 7);
            gload_lds16(vt + ((size_t)bh * 128 + row) * 2048 + k0 + s * 8,
                        &Vts[buf][c * 8]);
        }
    };

    f32x16 oacc[4] = {};
    float lsum = 0.f;

    const int nit = 2 * t + 2;
    stageKV(0, 0);
    __syncthreads();
    int cur = 0;

    for (int it = 0; it < nit; ++it) {
        if (it + 1 < nit) stageKV(cur ^ 1, (it + 1) * 64);
        const int k0 = it * 64;

        if (k0 <= qbase + 31) {
            const bf16* Kc = &Ks[cur][0];
            const bf16* Vc = &Vts[cur][0];

            f32x16 sacc[2] = {};
            __builtin_amdgcn_s_setprio(1);
#pragma unroll
            for (int nt = 0; nt < 2; ++nt) {
#pragma unroll
                for (int s = 0; s < 8; ++s) {
                    const int sp = (2 * s + h) ^ (l31 & 15);
                    bf16x8 bk = *(const bf16x8*)(Kc + (nt * 32 + l31) * 128 + sp * 8);
                    sacc[nt] = MFMA32(bk, aq[s], sacc[nt]);
                }
            }
            __builtin_amdgcn_s_setprio(0);

            const bool needmask = (k0 + 63) > qbase;
            bf16x8 ap[4];
#pragma unroll
            for (int s4 = 0; s4 < 4; ++s4) {
                const int nt = s4 >> 1, base = (s4 & 1) * 8;
                float e[8];
#pragma unroll
                for (int k = 0; k < 8; ++k) {
                    const int c = base + k;
                    const int key = k0 + nt * 32 + (c & 3) + 8 * (c >> 2) + 4 * h;
                    float v = __expf(sacc[nt][c]);
                    if (needmask && key > qrow) v = 0.f;
                    e[k] = v;
                    lsum += v;
                }
                const int X0 = pack2(e[0], e[1]), X1 = pack2(e[2], e[3]);
                const int Y0 = pack2(e[4], e[5]), Y1 = pack2(e[6], e[7]);
                int W0 = h ? X0 : Y0, W1 = h ? X1 : Y1;
                W0 = __shfl_xor(W0, 32);
                W1 = __shfl_xor(W1, 32);
                union { intx4 w; bf16x8 v; } u;
                u.w[0] = h ? W0 : X0;
                u.w[1] = h ? W1 : X1;
                u.w[2] = h ? Y0 : W0;
                u.w[3] = h ? Y1 : W1;
                ap[s4] = u.v;
            }

            __builtin_amdgcn_s_setprio(1);
#pragma unroll
            for (int d0 = 0; d0 < 4; ++d0) {
#pragma unroll
                for (int ks = 0; ks < 4; ++ks) {
                    const int sp = (2 * ks + h) ^ (l31 & 7);
                    bf16x8 bv = *(const bf16x8*)(Vc + (d0 * 32 + l31) * 64 + sp * 8);
                    oacc[d0] = MFMA32(ap[ks], bv, oacc[d0]);
                }
            }
            __builtin_amdgcn_s_setprio(0);
        }

        __syncthreads();
        cur ^= 1;
    }

    lsum += __shfl_xor(lsum, 32);
    const float inv = 1.0f / lsum;
    float invr[16];
#pragma unroll
    for (int r = 0; r < 16; ++r)
        invr[r] = __shfl(inv, (r & 3) + 8 * (r >> 2) + 4 * h, 32);

#pragma unroll
    for (int d0 = 0; d0 < 4; ++d0) {
#pragma unroll
        for (int r = 0; r < 16; ++r) {
            const int rr = (r & 3) + 8 * (r >> 2) + 4 * h;
            o[(size_t)(b_ * 2048 + qbase + rr) * 2048 + hh * 128 + d0 * 32 + l31] =
                (bf16)(oacc[d0][r] * invr[r]);
        }
    }
}

// ---------------------------------------------------------------------------
extern "C" void kernel_launch(void* const* d_in, const int* in_sizes, int n_in,
                              void* d_out, int out_size, void* d_ws, size_t ws_size,
                              hipStream_t stream) {
    const float* x    = (const float*)d_in[0];  // [4096][2048] fp32
    const float* Wqkv = (const float*)d_in[1];  // [2048][6144] fp32
    const float* Wo   = (const float*)d_in[2];  // [2048][2048] fp32
    float* out        = (float*)d_out;          // [4096][2048] fp32

    char* ws = (char*)d_ws;
    bf16* xb    = (bf16*)ws; ws += (size_t)4096 * 2048 * 2;
    bf16* WqkvT = (bf16*)ws; ws += (size_t)6144 * 2048 * 2;
    bf16* WoT   = (bf16*)ws; ws += (size_t)2048 * 2048 * 2;
    bf16* qt    = (bf16*)ws; ws += (size_t)32 * 2048 * 128 * 2;
    bf16* kt    = (bf16*)ws; ws += (size_t)32 * 2048 * 128 * 2;
    bf16* vt    = (bf16*)ws; ws += (size_t)32 * 128 * 2048 * 2;
    bf16* ob    = (bf16*)ws; ws += (size_t)4096 * 2048 * 2;

    prep_kernel<<<24576, 256, 0, stream>>>(x, Wqkv, Wo, xb, WqkvT, WoT);

    gemm_bt_kernel<0><<<dim3(48, 32), 256, 0, stream>>>(
        xb, WqkvT, 4096, 6144, 2048, qt, kt, vt, nullptr);

    attn_kernel<<<dim3(32, 16), 256, 0, stream>>>(qt, kt, vt, ob);

    gemm_bt_kernel<1><<<dim3(16, 32), 256, 0, stream>>>(
        ob, WoT, 4096, 2048, 2048, nullptr, nullptr, nullptr, out);
}

// Round 9
// 364.206 us; speedup vs baseline: 1.0439x; 1.0439x over previous
//
#include <hip/hip_runtime.h>
#include <hip/hip_bf16.h>
#include <cstdint>

typedef __bf16 bf16;
typedef __bf16 bf16x8 __attribute__((ext_vector_type(8)));
typedef __bf16 bf16x4 __attribute__((ext_vector_type(4)));
typedef __bf16 bf16x2 __attribute__((ext_vector_type(2)));
typedef float floatx4 __attribute__((ext_vector_type(4)));
typedef float f32x16 __attribute__((ext_vector_type(16)));
typedef int intx4 __attribute__((ext_vector_type(4)));

#define MFMA16(a, b, c) __builtin_amdgcn_mfma_f32_16x16x32_bf16(a, b, c, 0, 0, 0)
#define MFMA32(a, b, c) __builtin_amdgcn_mfma_f32_32x32x16_bf16(a, b, c, 0, 0, 0)

__device__ __forceinline__ void gload_lds16(const void* g, void* l) {
    __builtin_amdgcn_global_load_lds(
        (const __attribute__((address_space(1))) void*)g,
        (__attribute__((address_space(3))) void*)l, 16, 0, 0);
}

__device__ __forceinline__ int pack2(float a, float b) {
    union { bf16x2 v; int u; } z;
    z.v[0] = (bf16)a;
    z.v[1] = (bf16)b;
    return z.u;
}

// ---------------------------------------------------------------------------
// Fused prep. R9: transposes retiled 64(r) x 32(c) so each wave's 64 lanes
// write 64 consecutive bf16 = 128 B contiguous stores (was 32x32 tiles ->
// 64 B segments, half a cacheline, over 56 MB of transposed weights).
// LDS tile[64][33]: load banks stride-1 (free), store-side read
// tile[lane][cc] has bank (lane+cc)%32 -> 2-way aliasing only (free, m136).
//   blocks [0, 8192):       downcast x -> xb
//   blocks [8192, 14336):   transpose Wqkv [2048][6144] -> WqkvT (192x32 tiles)
//   blocks [14336, 16384):  transpose Wo   [2048][2048] -> WoT   (64x32 tiles)
// ---------------------------------------------------------------------------
__global__ __launch_bounds__(256) void prep_kernel(
    const float* __restrict__ x, const float* __restrict__ Wqkv,
    const float* __restrict__ Wo, bf16* __restrict__ xb,
    bf16* __restrict__ WqkvT, bf16* __restrict__ WoT) {
    __shared__ float tile[64][33];
    const int bid = blockIdx.x;
    const int tid = threadIdx.x;

    if (bid < 8192) {
        const size_t i = ((size_t)bid * 256 + tid) * 4;
        const float4 v = *(const float4*)(x + i);
        bf16x4 o = {(bf16)v.x, (bf16)v.y, (bf16)v.z, (bf16)v.w};
        *(bf16x4*)(xb + i) = o;
        return;
    }

    const float* in;
    bf16* out;
    int R, C, r0, c0;
    if (bid < 14336) {
        const int b = bid - 8192;
        in = Wqkv; out = WqkvT; R = 2048; C = 6144;
        c0 = (b % 192) * 32; r0 = (b / 192) * 64;
    } else {
        const int b = bid - 14336;
        in = Wo; out = WoT; R = 2048; C = 2048;
        c0 = (b & 63) * 32; r0 = (b >> 6) * 64;
    }

    const int tx = tid & 31, ry = tid >> 5;  // ry = 0..7
#pragma unroll
    for (int p = 0; p < 8; ++p)
        tile[p * 8 + ry][tx] = in[(size_t)(r0 + p * 8 + ry) * C + (c0 + tx)];
    __syncthreads();

    const int lane = tid & 63, wv = tid >> 6;  // wv = 0..3
#pragma unroll
    for (int p = 0; p < 8; ++p) {
        const int cc = p * 4 + wv;
        out[(size_t)(c0 + cc) * R + (r0 + lane)] = (bf16)tile[lane][cc];
    }
}

// ---------------------------------------------------------------------------
// GEMM: C[M][N] = A[M][K] @ BT[N][K]^T   (bf16 in, fp32 accum)
// Verified 128x128 m97-structure (~117 us for qkv, 866 TF). The 256^2
// 8-phase was tried THREE times (R1/R5/R7: 140/149/144 us, MfmaUtil 28-29,
// invariant to wait discipline & stage placement) -> retired permanently.
// MODE 0: epilogue scatters to q/k/v (N = 6144 = [3][16][128])
// MODE 1: epilogue writes FP32 C row-major [M][N]
// ---------------------------------------------------------------------------
template <int MODE>
__global__ __launch_bounds__(256) void gemm_bt_kernel(
    const bf16* __restrict__ A, const bf16* __restrict__ BT,
    int M, int N, int K,
    bf16* __restrict__ qt, bf16* __restrict__ kt, bf16* __restrict__ vt,
    float* __restrict__ Cout) {
    __shared__ alignas(16) bf16 As[128 * 64];  // 16 KB
    __shared__ alignas(16) bf16 Bs[128 * 64];  // 16 KB

    const int tid = threadIdx.x;
    const int wave = tid >> 6, lane = tid & 63;
    const int quad = lane >> 4, r16 = lane & 15;
    const int m0 = blockIdx.y * 128, n0 = blockIdx.x * 128;
    const int wm = (wave >> 1) * 64, wn = (wave & 1) * 64;

    // staging map: 4 chunks per matrix per thread; chunk c: row=c>>3, sp=c&7,
    // global seg s = sp ^ (row&7)
    int srow[4], soff[4];
#pragma unroll
    for (int j = 0; j < 4; ++j) {
        const int c = tid + j * 256;
        srow[j] = c >> 3;
        soff[j] = ((c & 7) ^ (srow[j] & 7)) * 8;
    }

    floatx4 acc[4][4] = {};

    for (int k0 = 0; k0 < K; k0 += 64) {
        __syncthreads();
#pragma unroll
        for (int j = 0; j < 4; ++j) {
            const int c = tid + j * 256;
            gload_lds16(A + (size_t)(m0 + srow[j]) * K + k0 + soff[j], As + c * 8);
            gload_lds16(BT + (size_t)(n0 + srow[j]) * K + k0 + soff[j], Bs + c * 8);
        }
        __syncthreads();

#pragma unroll
        for (int kc = 0; kc < 2; ++kc) {
            bf16x8 a[4], b[4];
#pragma unroll
            for (int i = 0; i < 4; ++i) {
                const int row = wm + i * 16 + r16;
                const int sp = (4 * kc + quad) ^ (row & 7);
                a[i] = *(const bf16x8*)(As + row * 64 + sp * 8);
            }
#pragma unroll
            for (int j = 0; j < 4; ++j) {
                const int row = wn + j * 16 + r16;
                const int sp = (4 * kc + quad) ^ (row & 7);
                b[j] = *(const bf16x8*)(Bs + row * 64 + sp * 8);
            }
#pragma unroll
            for (int i = 0; i < 4; ++i)
#pragma unroll
                for (int j = 0; j < 4; ++j)
                    acc[i][j] = MFMA16(a[i], b[j], acc[i][j]);
        }
    }

    if (MODE == 0) {
        const int t = n0 >> 11;  // block-uniform: which of q/k/v
        const float qscale = 0.08838834764831845f;  // 128^-0.5
#pragma unroll
        for (int i = 0; i < 4; ++i) {
            const int mbase = m0 + wm + i * 16 + quad * 4;
            const int b_ = mbase >> 11;
            const int s = mbase & 2047;
#pragma unroll
            for (int j = 0; j < 4; ++j) {
                const int n = n0 + wn + j * 16 + r16;
                const int h = (n >> 7) & 15, hd = n & 127;
                const int bh = b_ * 16 + h;
                if (t == 0) {
#pragma unroll
                    for (int r = 0; r < 4; ++r)
                        qt[(size_t)(bh * 2048 + s + r) * 128 + hd] =
                            (bf16)(acc[i][j][r] * qscale);
                } else if (t == 1) {
#pragma unroll
                    for (int r = 0; r < 4; ++r)
                        kt[(size_t)(bh * 2048 + s + r) * 128 + hd] = (bf16)acc[i][j][r];
                } else {
                    bf16x4 pv = {(bf16)acc[i][j][0], (bf16)acc[i][j][1],
                                 (bf16)acc[i][j][2], (bf16)acc[i][j][3]};
                    *(bf16x4*)(vt + (size_t)(bh * 128 + hd) * 2048 + s) = pv;
                }
            }
        }
    } else {
#pragma unroll
        for (int i = 0; i < 4; ++i) {
            const int mbase = m0 + wm + i * 16 + quad * 4;
#pragma unroll
            for (int j = 0; j < 4; ++j) {
                const int n = n0 + wn + j * 16 + r16;
#pragma unroll
                for (int r = 0; r < 4; ++r)
                    Cout[(size_t)(mbase + r) * N + n] = acc[i][j][r];
            }
        }
    }
}

// ---------------------------------------------------------------------------
// Flash attention (causal), no-max softmax. Byte-identical to R6 (362.8 us
// best): swapped QK^T (32x32x16), in-register P via pack+shfl_xor(32), K/V
// dbuf stage-early pipeline, by->t pairing, 64 KB LDS, 2 blocks/CU.
// R8's XCD remap regressed +17 us -> dropped (default dispatch already
// co-locates same-bh blocks per XCD: xcd = (by*32+bh)&7 = bh&7).
// ---------------------------------------------------------------------------
__global__ __launch_bounds__(256, 2) void attn_kernel(
    const bf16* __restrict__ qt, const bf16* __restrict__ kt,
    const bf16* __restrict__ vt, bf16* __restrict__ o) {
    __shared__ alignas(16) bf16 Ks[2][64 * 128];   // (row,sp): seg = sp ^ (row&15)
    __shared__ alignas(16) bf16 Vts[2][128 * 64];  // (row,sp): seg = sp ^ (row&7)

    const int tid = threadIdx.x;
    const int wave = tid >> 6, lane = tid & 63;
    const int l31 = lane & 31, h = lane >> 5;
    const int bh = blockIdx.x, by = blockIdx.y;
    const int t = by < 8 ? by : 23 - by;
    const int b_ = bh >> 4, hh = bh & 15;

    const int q0 = t * 128;
    const int qbase = q0 + wave * 32;
    const int qrow = qbase + l31;

    bf16x8 aq[8];
    {
        const bf16* qr = qt + (((size_t)bh * 2048 + qrow) << 7);
#pragma unroll
        for (int s = 0; s < 8; ++s)
            aq[s] = *(const bf16x8*)(qr + s * 16 + h * 8);
    }

    auto stageKV = [&](int buf, int k0) {
#pragma unroll
        for (int j = 0; j < 4; ++j) {
            const int c = tid + j * 256;
            const int row = c >> 4, sp = c & 15, s = sp ^ (row & 15);
            gload_lds16(kt + (((size_t)bh * 2048 + k0 + row) << 7) + s * 8,
                        &Ks[buf][c * 8]);
        }
#pragma unroll
        for (int j = 0; j < 4; ++j) {
            const int c = tid + j * 256;
            const int row = c >> 3, sp = c & 7, s = sp ^ (row & 7);
            gload_lds16(vt + ((size_t)bh * 128 + row) * 2048 + k0 + s * 8,
                        &Vts[buf][c * 8]);
        }
    };

    f32x16 oacc[4] = {};
    float lsum = 0.f;

    const int nit = 2 * t + 2;
    stageKV(0, 0);
    __syncthreads();
    int cur = 0;

    for (int it = 0; it < nit; ++it) {
        if (it + 1 < nit) stageKV(cur ^ 1, (it + 1) * 64);
        const int k0 = it * 64;

        if (k0 <= qbase + 31) {
            const bf16* Kc = &Ks[cur][0];
            const bf16* Vc = &Vts[cur][0];

            f32x16 sacc[2] = {};
            __builtin_amdgcn_s_setprio(1);
#pragma unroll
            for (int nt = 0; nt < 2; ++nt) {
#pragma unroll
                for (int s = 0; s < 8; ++s) {
                    const int sp = (2 * s + h) ^ (l31 & 15);
                    bf16x8 bk = *(const bf16x8*)(Kc + (nt * 32 + l31) * 128 + sp * 8);
                    sacc[nt] = MFMA32(bk, aq[s], sacc[nt]);
                }
            }
            __builtin_amdgcn_s_setprio(0);

            const bool needmask = (k0 + 63) > qbase;
            bf16x8 ap[4];
#pragma unroll
            for (int s4 = 0; s4 < 4; ++s4) {
                const int nt = s4 >> 1, base = (s4 & 1) * 8;
                float e[8];
#pragma unroll
                for (int k = 0; k < 8; ++k) {
                    const int c = base + k;
                    const int key = k0 + nt * 32 + (c & 3) + 8 * (c >> 2) + 4 * h;
                    float v = __expf(sacc[nt][c]);
                    if (needmask && key > qrow) v = 0.f;
                    e[k] = v;
                    lsum += v;
                }
                const int X0 = pack2(e[0], e[1]), X1 = pack2(e[2], e[3]);
                const int Y0 = pack2(e[4], e[5]), Y1 = pack2(e[6], e[7]);
                int W0 = h ? X0 : Y0, W1 = h ? X1 : Y1;
                W0 = __shfl_xor(W0, 32);
                W1 = __shfl_xor(W1, 32);
                union { intx4 w; bf16x8 v; } u;
                u.w[0] = h ? W0 : X0;
                u.w[1] = h ? W1 : X1;
                u.w[2] = h ? Y0 : W0;
                u.w[3] = h ? Y1 : W1;
                ap[s4] = u.v;
            }

            __builtin_amdgcn_s_setprio(1);
#pragma unroll
            for (int d0 = 0; d0 < 4; ++d0) {
#pragma unroll
                for (int ks = 0; ks < 4; ++ks) {
                    const int sp = (2 * ks + h) ^ (l31 & 7);
                    bf16x8 bv = *(const bf16x8*)(Vc + (d0 * 32 + l31) * 64 + sp * 8);
                    oacc[d0] = MFMA32(ap[ks], bv, oacc[d0]);
                }
            }
            __builtin_amdgcn_s_setprio(0);
        }

        __syncthreads();
        cur ^= 1;
    }

    lsum += __shfl_xor(lsum, 32);
    const float inv = 1.0f / lsum;
    float invr[16];
#pragma unroll
    for (int r = 0; r < 16; ++r)
        invr[r] = __shfl(inv, (r & 3) + 8 * (r >> 2) + 4 * h, 32);

#pragma unroll
    for (int d0 = 0; d0 < 4; ++d0) {
#pragma unroll
        for (int r = 0; r < 16; ++r) {
            const int rr = (r & 3) + 8 * (r >> 2) + 4 * h;
            o[(size_t)(b_ * 2048 + qbase + rr) * 2048 + hh * 128 + d0 * 32 + l31] =
                (bf16)(oacc[d0][r] * invr[r]);
        }
    }
}

// ---------------------------------------------------------------------------
extern "C" void kernel_launch(void* const* d_in, const int* in_sizes, int n_in,
                              void* d_out, int out_size, void* d_ws, size_t ws_size,
                              hipStream_t stream) {
    const float* x    = (const float*)d_in[0];  // [4096][2048] fp32
    const float* Wqkv = (const float*)d_in[1];  // [2048][6144] fp32
    const float* Wo   = (const float*)d_in[2];  // [2048][2048] fp32
    float* out        = (float*)d_out;          // [4096][2048] fp32

    char* ws = (char*)d_ws;
    bf16* xb    = (bf16*)ws; ws += (size_t)4096 * 2048 * 2;
    bf16* WqkvT = (bf16*)ws; ws += (size_t)6144 * 2048 * 2;
    bf16* WoT   = (bf16*)ws; ws += (size_t)2048 * 2048 * 2;
    bf16* qt    = (bf16*)ws; ws += (size_t)32 * 2048 * 128 * 2;
    bf16* kt    = (bf16*)ws; ws += (size_t)32 * 2048 * 128 * 2;
    bf16* vt    = (bf16*)ws; ws += (size_t)32 * 128 * 2048 * 2;
    bf16* ob    = (bf16*)ws; ws += (size_t)4096 * 2048 * 2;

    prep_kernel<<<16384, 256, 0, stream>>>(x, Wqkv, Wo, xb, WqkvT, WoT);

    gemm_bt_kernel<0><<<dim3(48, 32), 256, 0, stream>>>(
        xb, WqkvT, 4096, 6144, 2048, qt, kt, vt, nullptr);

    attn_kernel<<<dim3(32, 16), 256, 0, stream>>>(qt, kt, vt, ob);

    gemm_bt_kernel<1><<<dim3(16, 32), 256, 0, stream>>>(
        ob, WoT, 4096, 2048, 2048, nullptr, nullptr, nullptr, out);
}